// Round 1
// baseline (200.095 us; speedup 1.0000x reference)
//
#include <hip/hip_runtime.h>
#include <stdint.h>

#define BATCH 32
#define TLEN  1024
#define DIN   512
#define DOUT  512
#define KW    5
#define TOUT  1020          // TLEN - KW + 1
#define KDIM  (DIN * KW)    // 2560

// 256x256 tile, 8-phase counted-vmcnt schedule (T2+T3+T4+T5)
#define BM 256
#define BN 256
#define BK 64
#define NT (KDIM / BK)      // 40 K-tiles
#define TILE_E (BM * BK)    // 16384 bf16 elems per buffer per matrix (32 KB)

typedef __attribute__((ext_vector_type(8))) short bf16x8;
typedef __attribute__((ext_vector_type(4))) float f32x4;

__device__ __forceinline__ uint16_t f2bf(float f) {
    uint32_t u = __float_as_uint(f);
    uint32_t r = u + 0x7FFFu + ((u >> 16) & 1u);   // RNE to bf16
    return (uint16_t)(r >> 16);
}

// Fused: blocks [0,8192) convert x fp32->bf16 (8 elem/thread);
//        blocks [8192,13312) pack W [DOUT,DIN,KW] -> Wb[o][k*512+i] bf16.
__global__ void convert_pack(const float4* __restrict__ x, uint4* __restrict__ xb,
                             const float* __restrict__ w, uint16_t* __restrict__ wb) {
    int bid = blockIdx.x;
    if (bid < 8192) {
        int idx = bid * 256 + threadIdx.x;          // 0 .. 2097151 exact
        float4 a = x[2 * idx];
        float4 b = x[2 * idx + 1];
        uint4 v;
        v.x = (uint32_t)f2bf(a.x) | ((uint32_t)f2bf(a.y) << 16);
        v.y = (uint32_t)f2bf(a.z) | ((uint32_t)f2bf(a.w) << 16);
        v.z = (uint32_t)f2bf(b.x) | ((uint32_t)f2bf(b.y) << 16);
        v.w = (uint32_t)f2bf(b.z) | ((uint32_t)f2bf(b.w) << 16);
        xb[idx] = v;
    } else {
        int idx = (bid - 8192) * 256 + threadIdx.x; // 0 .. 1310719 exact
        int o   = idx / KDIM;
        int rem = idx - o * KDIM;
        int k   = rem >> 9;
        int i   = rem & 511;
        wb[idx] = f2bf(w[(o * DIN + i) * KW + k]);
    }
}

// ---------------------------------------------------------------------------
// GEMM: C[m=(b,t), n=o] = sum_k xflat[b, t*512+k] * Wb[n][k]   (im2col view)
//
// 256x256x(BK=64) tile, 8 waves (2M x 4N), double-buffered 128 KiB LDS.
// LDS row order is permuted so each 16 KB staging half is consumed by exactly
// one phase:  A lds row = mh*128 + wm*64 + q   (tile row = wm*128 + mh*64 + q)
//             B lds row = nh*128 + wn*32 + q   (tile row = wn*64 + nh*32 + q)
// Phase reads:  p0: A-H0 + B-H0   p1: B-H1   p2: A-H1   p3: B-H0 (again)
// Stage issues: p0: (kt+1).B-H0 -> other buf        (B-H0 freed at kt-1.p3)
//               p1: (kt+2).A-H0 -> this buf         (freed at kt.p0)
//               p2: (kt+2).B-H1 -> this buf         (freed at kt.p1)
//               p3: (kt+2).A-H1 -> this buf         (freed at kt.p2)
// One vmcnt per K-tile at p3 end: vmcnt(6) = 3 half-tiles (2 loads each) in
// flight; everything through (kt+1).B-H0 has landed. Never vmcnt(0) mid-loop.
// Chunk XOR swizzle (slot = chunk ^ (row&7)) applied on BOTH the pre-swizzled
// global source and the ds_read address (verified 0 bank conflicts).
// ---------------------------------------------------------------------------

#define STAGE_A(buf_, mh_, kt_) do {                                           \
    const uint16_t* lb_ = As_ + (buf_) * TILE_E + (mh_) * 8192;                \
    _Pragma("unroll")                                                          \
    for (int ii = 0; ii < 2; ++ii) {                                          \
        int c_  = ii * 512 + w * 64 + lane;                                   \
        int rh_ = c_ >> 3;                                                    \
        int g_  = (c_ & 7) ^ (rh_ & 7);                                       \
        int gr_ = ((rh_ >> 6) << 7) + (mh_) * 64 + (rh_ & 63);                \
        const uint16_t* gp_ = xrow + (size_t)gr_ * DIN + (kt_) * BK + g_ * 8; \
        const uint16_t* lp_ = lb_ + (ii * 512 + w * 64) * 8;                  \
        __builtin_amdgcn_global_load_lds(                                     \
            (const __attribute__((address_space(1))) void*)gp_,               \
            (__attribute__((address_space(3))) void*)lp_, 16, 0, 0);          \
    }                                                                          \
} while (0)

#define STAGE_B(buf_, nh_, kt_) do {                                           \
    const uint16_t* lb_ = Bs_ + (buf_) * TILE_E + (nh_) * 8192;                \
    _Pragma("unroll")                                                          \
    for (int ii = 0; ii < 2; ++ii) {                                          \
        int c_  = ii * 512 + w * 64 + lane;                                   \
        int rh_ = c_ >> 3;                                                    \
        int g_  = (c_ & 7) ^ (rh_ & 7);                                       \
        int gr_ = ((rh_ >> 5) << 6) + (nh_) * 32 + (rh_ & 31);                \
        const uint16_t* gp_ = wrow + (size_t)gr_ * KDIM + (kt_) * BK + g_ * 8;\
        const uint16_t* lp_ = lb_ + (ii * 512 + w * 64) * 8;                  \
        __builtin_amdgcn_global_load_lds(                                     \
            (const __attribute__((address_space(1))) void*)gp_,               \
            (__attribute__((address_space(3))) void*)lp_, 16, 0, 0);          \
    }                                                                          \
} while (0)

#define LDA(buf_, mh_) do {                                                    \
    const uint16_t* Ab_ = As_ + (buf_) * TILE_E;                               \
    _Pragma("unroll")                                                          \
    for (int mi = 0; mi < 4; ++mi) {                                          \
        int r_ = (mh_) * 128 + wm * 64 + mi * 16 + ml;                        \
        _Pragma("unroll")                                                      \
        for (int h2 = 0; h2 < 2; ++h2) {                                     \
            int cc_ = h2 * 4 + kg;                                            \
            af[mi][h2] = *(const bf16x8*)&Ab_[r_ * BK + ((cc_ ^ (r_ & 7)) * 8)];\
        }                                                                      \
    }                                                                          \
} while (0)

#define LDB(buf_, nh_) do {                                                    \
    const uint16_t* Bb_ = Bs_ + (buf_) * TILE_E;                               \
    _Pragma("unroll")                                                          \
    for (int ni = 0; ni < 2; ++ni) {                                          \
        int r_ = (nh_) * 128 + wn * 32 + ni * 16 + ml;                        \
        _Pragma("unroll")                                                      \
        for (int h2 = 0; h2 < 2; ++h2) {                                     \
            int cc_ = h2 * 4 + kg;                                            \
            bfr[ni][h2] = *(const bf16x8*)&Bb_[r_ * BK + ((cc_ ^ (r_ & 7)) * 8)];\
        }                                                                      \
    }                                                                          \
} while (0)

#define MMA(mh_, nh_) do {                                                     \
    _Pragma("unroll")                                                          \
    for (int h2 = 0; h2 < 2; ++h2)                                            \
        _Pragma("unroll")                                                      \
        for (int mi = 0; mi < 4; ++mi)                                        \
            _Pragma("unroll")                                                  \
            for (int ni = 0; ni < 2; ++ni)                                    \
                acc[(mh_) * 4 + mi][(nh_) * 2 + ni] =                         \
                    __builtin_amdgcn_mfma_f32_16x16x32_bf16(                  \
                        af[mi][h2], bfr[ni][h2],                              \
                        acc[(mh_) * 4 + mi][(nh_) * 2 + ni], 0, 0, 0);        \
} while (0)

// barrier -> drain own ds_reads -> fence (rule 18) before the MFMA cluster
#define BARW() do {                                                            \
    __builtin_amdgcn_s_barrier();                                              \
    asm volatile("s_waitcnt lgkmcnt(0)" ::: "memory");                         \
    __builtin_amdgcn_sched_barrier(0);                                         \
} while (0)

// One K-tile = 4 phases. KT_B/GB: (kt+1).B-H0 stage into the OTHER buffer.
// KT_A/GA: (kt+2) stages into THIS buffer. VM6: steady-state counted wait.
#define DO_KTILE(BUF, KT_B, GB, KT_A, GA, VM6)                                 \
    /* p0: quadrant (m0,n0) */                                                 \
    LDA(BUF, 0); LDB(BUF, 0);                                                  \
    if (GB) STAGE_B(1 - (BUF), 0, KT_B);                                       \
    BARW();                                                                    \
    __builtin_amdgcn_s_setprio(1); MMA(0, 0); __builtin_amdgcn_s_setprio(0);   \
    __builtin_amdgcn_s_barrier();                                              \
    /* p1: (m0,n1) */                                                          \
    LDB(BUF, 1);                                                               \
    if (GA) STAGE_A(BUF, 0, KT_A);                                             \
    BARW();                                                                    \
    __builtin_amdgcn_s_setprio(1); MMA(0, 1); __builtin_amdgcn_s_setprio(0);   \
    __builtin_amdgcn_s_barrier();                                              \
    /* p2: (m1,n1) */                                                          \
    LDA(BUF, 1);                                                               \
    if (GA) STAGE_B(BUF, 1, KT_A);                                             \
    BARW();                                                                    \
    __builtin_amdgcn_s_setprio(1); MMA(1, 1); __builtin_amdgcn_s_setprio(0);   \
    __builtin_amdgcn_s_barrier();                                              \
    /* p3: (m1,n0) */                                                          \
    LDB(BUF, 0);                                                               \
    if (GA) STAGE_A(BUF, 1, KT_A);                                             \
    BARW();                                                                    \
    __builtin_amdgcn_s_setprio(1); MMA(1, 0); __builtin_amdgcn_s_setprio(0);   \
    if (VM6) { asm volatile("s_waitcnt vmcnt(6)" ::: "memory"); }              \
    else     { asm volatile("s_waitcnt vmcnt(0)" ::: "memory"); }              \
    __builtin_amdgcn_s_barrier();                                              \
    __builtin_amdgcn_sched_barrier(0);

__global__ void __launch_bounds__(512, 2)
tdnn_gemm(const uint16_t* __restrict__ xb,
          const uint16_t* __restrict__ wb,
          const float* __restrict__ bias,
          float* __restrict__ out) {
    __shared__ uint16_t As_[2 * TILE_E];   // 64 KB (double-buffered A)
    __shared__ uint16_t Bs_[2 * TILE_E];   // 64 KB (double-buffered B)

    // XCD-aware swizzle: 256 blocks, 32/XCD; the 2 N-tiles of one M-tile are
    // adjacent on the same XCD (A-panel L2 reuse), B fits every XCD L2.
    const int j  = blockIdx.x;             // 0..255
    const int g  = (j & 7) * 32 + (j >> 3);
    const int mt = g >> 1;                 // 0..127
    const int nt = g & 1;
    const int b  = mt >> 2;
    const int t0 = (mt & 3) * BM;
    const int n0 = nt * BN;

    const int tid  = threadIdx.x;
    const int lane = tid & 63;
    const int w    = tid >> 6;             // wave 0..7
    const int wm   = w >> 2;               // 0..1
    const int wn   = w & 3;                // 0..3
    const int ml   = lane & 15;
    const int kg   = lane >> 4;            // 16B-chunk group within K=32

    const uint16_t* xrow = xb + (size_t)b * TLEN * DIN + (size_t)t0 * DIN;
    const uint16_t* wrow = wb + (size_t)n0 * KDIM;

    f32x4 acc[8][4] = {};
    bf16x8 af[4][2];
    bf16x8 bfr[2][2];

    // Prologue: kt0 fully + kt1.{A-H0,B-H1,A-H1}; kt1.B-H0 is issued at kt0.p0.
    // vmcnt(6): 3 newest halves (kt1's) may fly, kt0's 4 halves have landed.
    STAGE_A(0, 0, 0);
    STAGE_B(0, 0, 0);
    STAGE_A(0, 1, 0);
    STAGE_B(0, 1, 0);
    STAGE_A(1, 0, 1);
    STAGE_B(1, 1, 1);
    STAGE_A(1, 1, 1);
    asm volatile("s_waitcnt vmcnt(6)" ::: "memory");
    __builtin_amdgcn_s_barrier();
    __builtin_amdgcn_sched_barrier(0);

    for (int kt = 0; kt < NT; kt += 2) {
        const bool ga0 = (kt + 2) < NT;
        const bool ga1 = (kt + 3) < NT;
        DO_KTILE(0, kt + 1, true, kt + 2, ga0, ga0)
        DO_KTILE(1, kt + 2, ga0,  kt + 3, ga1, ga1)
    }

    // Epilogue. D map: col=lane&15 -> o, row=(lane>>4)*4+r -> t (contig in t,
    // so float4 stores; tbase%4==0 always, and the t>=1020 tail is a whole
    // skipped float4 since 1020%4==0).
    const int rq = (lane >> 4) * 4;
    #pragma unroll
    for (int nf = 0; nf < 4; ++nf) {
        const int o = n0 + wn * 64 + (nf >> 1) * 32 + (nf & 1) * 16 + ml;
        const float bv = bias[o];
        float* orow = out + ((size_t)b * DOUT + o) * TOUT;
        #pragma unroll
        for (int mf = 0; mf < 8; ++mf) {
            const int tb_ = t0 + wm * 128 + (mf >> 2) * 64 + (mf & 3) * 16 + rq;
            if (tb_ + 3 < TOUT) {
                float4 s;
                s.x = fmaxf(acc[mf][nf][0] + bv, 0.0f);
                s.y = fmaxf(acc[mf][nf][1] + bv, 0.0f);
                s.z = fmaxf(acc[mf][nf][2] + bv, 0.0f);
                s.w = fmaxf(acc[mf][nf][3] + bv, 0.0f);
                *(float4*)(orow + tb_) = s;
            }
        }
    }
}

extern "C" void kernel_launch(void* const* d_in, const int* in_sizes, int n_in,
                              void* d_out, int out_size, void* d_ws, size_t ws_size,
                              hipStream_t stream) {
    const float* x    = (const float*)d_in[0];
    const float* wgt  = (const float*)d_in[1];
    const float* bias = (const float*)d_in[2];
    float* out = (float*)d_out;

    // ws layout: xb first (b=31 im2col tail over-read lands in wb, not OOB)
    uint16_t* xb = (uint16_t*)d_ws;                                   // 33.55 MB
    uint16_t* wb = (uint16_t*)((char*)d_ws + (size_t)BATCH * TLEN * DIN * 2);

    convert_pack<<<13312, 256, 0, stream>>>((const float4*)x, (uint4*)xb, wgt, wb);
    tdnn_gemm<<<256, 512, 0, stream>>>(xb, wb, bias, out);
}

// Round 2
// 198.413 us; speedup vs baseline: 1.0085x; 1.0085x over previous
//
#include <hip/hip_runtime.h>
#include <stdint.h>

#define BATCH 32
#define TLEN  1024
#define DIN   512
#define DOUT  512
#define KW    5
#define TOUT  1020          // TLEN - KW + 1
#define KDIM  (DIN * KW)    // 2560

// 256x256 tile, 8-phase counted-vmcnt schedule (T2+T3+T4+T5)
#define BM 256
#define BN 256
#define BK 64
#define NT (KDIM / BK)      // 40 K-tiles
#define TILE_E (BM * BK)    // 16384 bf16 elems per buffer per matrix (32 KB)

typedef __attribute__((ext_vector_type(8))) short bf16x8;
typedef __attribute__((ext_vector_type(4))) float f32x4;

__device__ __forceinline__ uint16_t f2bf(float f) {
    uint32_t u = __float_as_uint(f);
    uint32_t r = u + 0x7FFFu + ((u >> 16) & 1u);   // RNE to bf16
    return (uint16_t)(r >> 16);
}

// Grid-strided fat-block convert+pack (G11: dispatch overhead, not memory,
// dominated the old 13312-WG version).
//  x-part: 8 units/block, each unit = 256 threads x 8 elems, vectorized.
//  W-part: 1 slab/block = (o, half): read 1280 contiguous floats coalesced
//          into LDS, transpose [i'][k] -> [k][i'] on write side; both global
//          sides fully coalesced. LDS stride-5 reads = 2/bank = free.
__global__ void __launch_bounds__(256)
convert_pack(const float4* __restrict__ x, uint4* __restrict__ xb,
             const float* __restrict__ w, uint16_t* __restrict__ wb) {
    const int tid = threadIdx.x;

    // ---- x: fp32 -> bf16, 2,097,152 uint4 units of 8 elems ----
    for (int u = blockIdx.x; u < 8192; u += 1024) {
        int idx = u * 256 + tid;
        float4 a = x[2 * idx];
        float4 b = x[2 * idx + 1];
        uint4 v;
        v.x = (uint32_t)f2bf(a.x) | ((uint32_t)f2bf(a.y) << 16);
        v.y = (uint32_t)f2bf(a.z) | ((uint32_t)f2bf(a.w) << 16);
        v.z = (uint32_t)f2bf(b.x) | ((uint32_t)f2bf(b.y) << 16);
        v.w = (uint32_t)f2bf(b.z) | ((uint32_t)f2bf(b.w) << 16);
        xb[idx] = v;
    }

    // ---- W: [DOUT][DIN][KW] fp32 -> Wb[o][k*512+i] bf16 ----
    __shared__ float4 lw4[320];        // 1280 floats = one (o, half) slab
    float* lw = (float*)lw4;
    const int o = blockIdx.x >> 1;     // 0..511
    const int h = blockIdx.x & 1;      // i-half
    const float4* src = (const float4*)(w + (size_t)o * KDIM + h * 1280);
    #pragma unroll
    for (int j = tid; j < 320; j += 256) lw4[j] = src[j];
    __syncthreads();
    // thread t owns i' = h*256+t; lw[t*5+k] = w[o][i'][k]
    #pragma unroll
    for (int k = 0; k < KW; ++k)
        wb[(size_t)o * KDIM + k * DIN + h * 256 + tid] = f2bf(lw[tid * 5 + k]);
}

// ---------------------------------------------------------------------------
// GEMM: C[m=(b,t), n=o] = sum_k xflat[b, t*512+k] * Wb[n][k]   (im2col view)
//
// 256x256x(BK=64) tile, 8 waves (2M x 4N), double-buffered 128 KiB LDS.
// LDS row order is permuted so each 16 KB staging half is consumed by exactly
// one phase:  A lds row = mh*128 + wm*64 + q   (tile row = wm*128 + mh*64 + q)
//             B lds row = nh*128 + wn*32 + q   (tile row = wn*64 + nh*32 + q)
// Phase reads:  p0: A-H0 + B-H0   p1: B-H1   p2: A-H1   p3: B-H0 (again)
// Stage issues: p0: (kt+1).B-H0 -> other buf        (B-H0 freed at kt-1.p3)
//               p1: (kt+2).A-H0 -> this buf         (freed at kt.p0)
//               p2: (kt+2).B-H1 -> this buf         (freed at kt.p1)
//               p3: (kt+2).A-H1 -> this buf         (freed at kt.p2)
// One vmcnt per K-tile at p3 end: vmcnt(6) = 3 half-tiles (2 loads each) in
// flight; everything through (kt+1).B-H0 has landed. Never vmcnt(0) mid-loop.
// Chunk XOR swizzle (slot = chunk ^ (row&7)) applied on BOTH the pre-swizzled
// global source and the ds_read address (verified 0 bank conflicts).
// ---------------------------------------------------------------------------

#define STAGE_A(buf_, mh_, kt_) do {                                           \
    const uint16_t* lb_ = As_ + (buf_) * TILE_E + (mh_) * 8192;                \
    _Pragma("unroll")                                                          \
    for (int ii = 0; ii < 2; ++ii) {                                          \
        int c_  = ii * 512 + w * 64 + lane;                                   \
        int rh_ = c_ >> 3;                                                    \
        int g_  = (c_ & 7) ^ (rh_ & 7);                                       \
        int gr_ = ((rh_ >> 6) << 7) + (mh_) * 64 + (rh_ & 63);                \
        const uint16_t* gp_ = xrow + (size_t)gr_ * DIN + (kt_) * BK + g_ * 8; \
        const uint16_t* lp_ = lb_ + (ii * 512 + w * 64) * 8;                  \
        __builtin_amdgcn_global_load_lds(                                     \
            (const __attribute__((address_space(1))) void*)gp_,               \
            (__attribute__((address_space(3))) void*)lp_, 16, 0, 0);          \
    }                                                                          \
} while (0)

#define STAGE_B(buf_, nh_, kt_) do {                                           \
    const uint16_t* lb_ = Bs_ + (buf_) * TILE_E + (nh_) * 8192;                \
    _Pragma("unroll")                                                          \
    for (int ii = 0; ii < 2; ++ii) {                                          \
        int c_  = ii * 512 + w * 64 + lane;                                   \
        int rh_ = c_ >> 3;                                                    \
        int g_  = (c_ & 7) ^ (rh_ & 7);                                       \
        int gr_ = ((rh_ >> 5) << 6) + (nh_) * 32 + (rh_ & 31);                \
        const uint16_t* gp_ = wrow + (size_t)gr_ * KDIM + (kt_) * BK + g_ * 8;\
        const uint16_t* lp_ = lb_ + (ii * 512 + w * 64) * 8;                  \
        __builtin_amdgcn_global_load_lds(                                     \
            (const __attribute__((address_space(1))) void*)gp_,               \
            (__attribute__((address_space(3))) void*)lp_, 16, 0, 0);          \
    }                                                                          \
} while (0)

#define LDA(buf_, mh_) do {                                                    \
    const uint16_t* Ab_ = As_ + (buf_) * TILE_E;                               \
    _Pragma("unroll")                                                          \
    for (int mi = 0; mi < 4; ++mi) {                                          \
        int r_ = (mh_) * 128 + wm * 64 + mi * 16 + ml;                        \
        _Pragma("unroll")                                                      \
        for (int h2 = 0; h2 < 2; ++h2) {                                     \
            int cc_ = h2 * 4 + kg;                                            \
            af[mi][h2] = *(const bf16x8*)&Ab_[r_ * BK + ((cc_ ^ (r_ & 7)) * 8)];\
        }                                                                      \
    }                                                                          \
} while (0)

#define LDB(buf_, nh_) do {                                                    \
    const uint16_t* Bb_ = Bs_ + (buf_) * TILE_E;                               \
    _Pragma("unroll")                                                          \
    for (int ni = 0; ni < 2; ++ni) {                                          \
        int r_ = (nh_) * 128 + wn * 32 + ni * 16 + ml;                        \
        _Pragma("unroll")                                                      \
        for (int h2 = 0; h2 < 2; ++h2) {                                     \
            int cc_ = h2 * 4 + kg;                                            \
            bfr[ni][h2] = *(const bf16x8*)&Bb_[r_ * BK + ((cc_ ^ (r_ & 7)) * 8)];\
        }                                                                      \
    }                                                                          \
} while (0)

#define MMA(mh_, nh_) do {                                                     \
    _Pragma("unroll")                                                          \
    for (int h2 = 0; h2 < 2; ++h2)                                            \
        _Pragma("unroll")                                                      \
        for (int mi = 0; mi < 4; ++mi)                                        \
            _Pragma("unroll")                                                  \
            for (int ni = 0; ni < 2; ++ni)                                    \
                acc[(mh_) * 4 + mi][(nh_) * 2 + ni] =                         \
                    __builtin_amdgcn_mfma_f32_16x16x32_bf16(                  \
                        af[mi][h2], bfr[ni][h2],                              \
                        acc[(mh_) * 4 + mi][(nh_) * 2 + ni], 0, 0, 0);        \
} while (0)

// barrier -> drain own ds_reads -> fence (rule 18) before the MFMA cluster
#define BARW() do {                                                            \
    __builtin_amdgcn_s_barrier();                                              \
    asm volatile("s_waitcnt lgkmcnt(0)" ::: "memory");                         \
    __builtin_amdgcn_sched_barrier(0);                                         \
} while (0)

// One K-tile = 4 phases. KT_B/GB: (kt+1).B-H0 stage into the OTHER buffer.
// KT_A/GA: (kt+2) stages into THIS buffer. VM6: steady-state counted wait.
#define DO_KTILE(BUF, KT_B, GB, KT_A, GA, VM6)                                 \
    /* p0: quadrant (m0,n0) — 12 ds_reads: partial pre-drain per template */   \
    LDA(BUF, 0); LDB(BUF, 0);                                                  \
    if (GB) STAGE_B(1 - (BUF), 0, KT_B);                                       \
    asm volatile("s_waitcnt lgkmcnt(8)" ::: "memory");                         \
    BARW();                                                                    \
    __builtin_amdgcn_s_setprio(1); MMA(0, 0); __builtin_amdgcn_s_setprio(0);   \
    __builtin_amdgcn_s_barrier();                                              \
    /* p1: (m0,n1) */                                                          \
    LDB(BUF, 1);                                                               \
    if (GA) STAGE_A(BUF, 0, KT_A);                                             \
    BARW();                                                                    \
    __builtin_amdgcn_s_setprio(1); MMA(0, 1); __builtin_amdgcn_s_setprio(0);   \
    __builtin_amdgcn_s_barrier();                                              \
    /* p2: (m1,n1) */                                                          \
    LDA(BUF, 1);                                                               \
    if (GA) STAGE_B(BUF, 1, KT_A);                                             \
    BARW();                                                                    \
    __builtin_amdgcn_s_setprio(1); MMA(1, 1); __builtin_amdgcn_s_setprio(0);   \
    __builtin_amdgcn_s_barrier();                                              \
    /* p3: (m1,n0) */                                                          \
    LDB(BUF, 0);                                                               \
    if (GA) STAGE_A(BUF, 1, KT_A);                                             \
    BARW();                                                                    \
    __builtin_amdgcn_s_setprio(1); MMA(1, 0); __builtin_amdgcn_s_setprio(0);   \
    if (VM6) { asm volatile("s_waitcnt vmcnt(6)" ::: "memory"); }              \
    else     { asm volatile("s_waitcnt vmcnt(0)" ::: "memory"); }              \
    __builtin_amdgcn_s_barrier();                                              \
    __builtin_amdgcn_sched_barrier(0);

__global__ void __launch_bounds__(512, 2)
tdnn_gemm(const uint16_t* __restrict__ xb,
          const uint16_t* __restrict__ wb,
          const float* __restrict__ bias,
          float* __restrict__ out) {
    __shared__ uint16_t As_[2 * TILE_E];   // 64 KB (double-buffered A)
    __shared__ uint16_t Bs_[2 * TILE_E];   // 64 KB (double-buffered B)

    // XCD-aware swizzle: 256 blocks, 32/XCD; the 2 N-tiles of one M-tile are
    // adjacent on the same XCD (A-panel L2 reuse), B fits every XCD L2.
    const int j  = blockIdx.x;             // 0..255
    const int g  = (j & 7) * 32 + (j >> 3);
    const int mt = g >> 1;                 // 0..127
    const int nt = g & 1;
    const int b  = mt >> 2;
    const int t0 = (mt & 3) * BM;
    const int n0 = nt * BN;

    const int tid  = threadIdx.x;
    const int lane = tid & 63;
    const int w    = tid >> 6;             // wave 0..7
    const int wm   = w >> 2;               // 0..1
    const int wn   = w & 3;                // 0..3
    const int ml   = lane & 15;
    const int kg   = lane >> 4;            // 16B-chunk group within K=32

    const uint16_t* xrow = xb + (size_t)b * TLEN * DIN + (size_t)t0 * DIN;
    const uint16_t* wrow = wb + (size_t)n0 * KDIM;

    f32x4 acc[8][4] = {};
    bf16x8 af[4][2];
    bf16x8 bfr[2][2];

    // Prologue: kt0 fully + kt1.{A-H0,B-H1,A-H1}; kt1.B-H0 is issued at kt0.p0.
    // vmcnt(6): 3 newest halves (kt1's) may fly, kt0's 4 halves have landed.
    STAGE_A(0, 0, 0);
    STAGE_B(0, 0, 0);
    STAGE_A(0, 1, 0);
    STAGE_B(0, 1, 0);
    STAGE_A(1, 0, 1);
    STAGE_B(1, 1, 1);
    STAGE_A(1, 1, 1);
    asm volatile("s_waitcnt vmcnt(6)" ::: "memory");
    __builtin_amdgcn_s_barrier();
    __builtin_amdgcn_sched_barrier(0);

    for (int kt = 0; kt < NT; kt += 2) {
        const bool ga0 = (kt + 2) < NT;
        const bool ga1 = (kt + 3) < NT;
        DO_KTILE(0, kt + 1, true, kt + 2, ga0, ga0)
        DO_KTILE(1, kt + 2, ga0,  kt + 3, ga1, ga1)
    }

    // Epilogue. D map: col=lane&15 -> o, row=(lane>>4)*4+r -> t (contig in t,
    // so float4 stores; tbase%4==0 always, and the t>=1020 tail is a whole
    // skipped float4 since 1020%4==0).
    const int rq = (lane >> 4) * 4;
    #pragma unroll
    for (int nf = 0; nf < 4; ++nf) {
        const int o = n0 + wn * 64 + (nf >> 1) * 32 + (nf & 1) * 16 + ml;
        const float bv = bias[o];
        float* orow = out + ((size_t)b * DOUT + o) * TOUT;
        #pragma unroll
        for (int mf = 0; mf < 8; ++mf) {
            const int tb_ = t0 + wm * 128 + (mf >> 2) * 64 + (mf & 3) * 16 + rq;
            if (tb_ + 3 < TOUT) {
                float4 s;
                s.x = fmaxf(acc[mf][nf][0] + bv, 0.0f);
                s.y = fmaxf(acc[mf][nf][1] + bv, 0.0f);
                s.z = fmaxf(acc[mf][nf][2] + bv, 0.0f);
                s.w = fmaxf(acc[mf][nf][3] + bv, 0.0f);
                *(float4*)(orow + tb_) = s;
            }
        }
    }
}

extern "C" void kernel_launch(void* const* d_in, const int* in_sizes, int n_in,
                              void* d_out, int out_size, void* d_ws, size_t ws_size,
                              hipStream_t stream) {
    const float* x    = (const float*)d_in[0];
    const float* wgt  = (const float*)d_in[1];
    const float* bias = (const float*)d_in[2];
    float* out = (float*)d_out;

    // ws layout: xb first (b=31 im2col tail over-read lands in wb, not OOB)
    uint16_t* xb = (uint16_t*)d_ws;                                   // 33.55 MB
    uint16_t* wb = (uint16_t*)((char*)d_ws + (size_t)BATCH * TLEN * DIN * 2);

    convert_pack<<<1024, 256, 0, stream>>>((const float4*)x, (uint4*)xb, wgt, wb);
    tdnn_gemm<<<256, 512, 0, stream>>>(xb, wb, bias, out);
}